// Round 25
// baseline (410.789 us; speedup 1.0000x reference)
//
#include <hip/hip_runtime.h>
#include <hip/hip_bf16.h>

// ---------------------------------------------------------------------------
// ROLAND-style GNN forward. Round 24: revert DMA-gather (R24: correct but
// slower -- gather is L3-service-bound, not ILP-bound; LDS round-trip was
// pure overhead). gather1 becomes FEATURE-SLICED: 8 slices x 32B, block
// bid -> (nodes bid>>3, slice bid&7). With round-robin bid%8 -> XCD, each
// XCD touches only its 1.6MB slice of hws1 -> L2-resident; row reads hit L2
// (34 TB/s) instead of re-fetching 151MB from L3. gather2 stays gather4<64>.
// GEMMs (BM=64 swizzled LDS DMA), build, decode8, workspace: identical R22.
// ---------------------------------------------------------------------------

typedef unsigned short ushort_t;
typedef __attribute__((ext_vector_type(8))) short s8v;   // 8 bf16 (4 VGPRs)
typedef __attribute__((ext_vector_type(4))) float f4;    // MFMA accumulator

#define BSHIFT 8                       // nodes per bucket = 256 (N<=65536)

__device__ __forceinline__ ushort_t f2bf(float v) {
    unsigned u = __float_as_uint(v);
    return (ushort_t)((u + 0x7FFFu + ((u >> 16) & 1u)) >> 16);
}

__device__ __forceinline__ s8v cvt8(f4 v0, f4 v1) {
    ushort_t hb[8];
    hb[0] = f2bf(v0.x); hb[1] = f2bf(v0.y); hb[2] = f2bf(v0.z); hb[3] = f2bf(v0.w);
    hb[4] = f2bf(v1.x); hb[5] = f2bf(v1.y); hb[6] = f2bf(v1.z); hb[7] = f2bf(v1.w);
    return *(s8v*)hb;
}

// swizzled ushort index within a row of width Wd: chunk c=(k&63)>>3 XOR row&7
__device__ __forceinline__ size_t swzidx(int row, int k, int Wd) {
    int p = (((k & 63) >> 3) ^ (row & 7));
    return (size_t)row * Wd + (k & ~63) + p * 8 + (k & 7);
}

// async 16B/lane global->LDS DMA; lds base wave-uniform, dest = base+lane*16
__device__ __forceinline__ void dma16(const ushort_t* g, ushort_t* l) {
    __builtin_amdgcn_global_load_lds(
        (const __attribute__((address_space(1))) unsigned int*)g,
        (__attribute__((address_space(3))) unsigned int*)l, 16, 0, 0);
}

// acc[8] += m * unpack8(uint4 of packed bf16 pairs)
__device__ __forceinline__ void add8(float* acc, uint4 u, float m) {
    acc[0] = fmaf(__uint_as_float(u.x << 16), m, acc[0]);
    acc[1] = fmaf(__uint_as_float(u.x & 0xFFFF0000u), m, acc[1]);
    acc[2] = fmaf(__uint_as_float(u.y << 16), m, acc[2]);
    acc[3] = fmaf(__uint_as_float(u.y & 0xFFFF0000u), m, acc[3]);
    acc[4] = fmaf(__uint_as_float(u.z << 16), m, acc[4]);
    acc[5] = fmaf(__uint_as_float(u.z & 0xFFFF0000u), m, acc[5]);
    acc[6] = fmaf(__uint_as_float(u.w << 16), m, acc[6]);
    acc[7] = fmaf(__uint_as_float(u.w & 0xFFFF0000u), m, acc[7]);
}

// ---------------- fp32 -> bf16 bulk convert (swizzled rows of width W) ------
template <int W>
__global__ __launch_bounds__(256) void f2bswz_kernel(const float* __restrict__ in,
                                                     ushort_t* __restrict__ out, size_t n) {
    size_t i = ((size_t)blockIdx.x * 256 + threadIdx.x) * 8;
    if (i + 8 > n) return;
    f4 v0 = *(const f4*)&in[i];
    f4 v1 = *(const f4*)&in[i + 4];
    int row = (int)(i / W), k = (int)(i % W);
    *(s8v*)&out[swzidx(row, k, W)] = cvt8(v0, v1);
}

// ---------------- LDS-staged MFMA GEMM (BM=64, single-buffer + swizzle) -----
template <int BN, int KW, int K1, bool A1F32, bool RELU, bool SCALE, bool DUAL,
          int OUTMODE, bool SWZO>
__global__ __launch_bounds__(256, 2) void gemm_lds(
    const float* __restrict__ A1f, const ushort_t* __restrict__ A1h,
    const ushort_t* __restrict__ A2h,
    const ushort_t* __restrict__ Wt,
    const float* __restrict__ bias, const float* __restrict__ rowscale,
    float* __restrict__ Cf, ushort_t* __restrict__ Ch,
    int M, int Nout)
{
    constexpr int NT = BN / 32;
    constexpr int K2 = KW - K1;
    __shared__ ushort_t Abuf[64 * 64];       // 8 KB
    __shared__ ushort_t Bbuf[BN * 64];       // 16/8 KB

    const int tid  = threadIdx.x;
    const int lane = tid & 63;
    const int w    = tid >> 6;
    const int wr   = w >> 1, wc = w & 1;
    const int rbase = blockIdx.y * 64;
    const int bn    = blockIdx.x * BN;

    f4 acc[2][NT];
    const f4 zero = {0.f, 0.f, 0.f, 0.f};
#pragma unroll
    for (int mi = 0; mi < 2; ++mi)
#pragma unroll
        for (int ni = 0; ni < NT; ++ni) acc[mi][ni] = zero;

    for (int kt = 0; kt < KW; kt += 64) {
        if constexpr (A1F32) {
#pragma unroll
            for (int j = 0; j < 2; ++j) {
                const int c2 = tid + j * 256;
                const int row = c2 >> 3, c = c2 & 7;
                const int gr = min(rbase + row, M - 1);
                const float* p = &A1f[(size_t)gr * K1 + kt + c * 8];
                const int pc = c ^ (row & 7);
                *(s8v*)&Abuf[row * 64 + pc * 8] = cvt8(*(const f4*)p, *(const f4*)(p + 4));
            }
        } else {
#pragma unroll
            for (int i = 0; i < 2; ++i) {
                const int s = w * 2 + i;
                const int row = s * 8 + (lane >> 3);
                const int c = lane & 7;
                const int gr = min(rbase + row, M - 1);
                const ushort_t* g;
                if (DUAL && kt >= K1) g = &A2h[(size_t)gr * K2 + (kt - K1) + c * 8];
                else                  g = &A1h[(size_t)gr * K1 + kt + c * 8];
                dma16(g, &Abuf[s * 512]);
            }
        }
#pragma unroll
        for (int i = 0; i < NT; ++i) {
            const int s = w * NT + i;
            const int colr = s * 8 + (lane >> 3);
            const int c = lane & 7;
            dma16(&Wt[(size_t)(bn + colr) * KW + kt + c * 8], &Bbuf[s * 512]);
        }
        __syncthreads();
#pragma unroll
        for (int ks = 0; ks < 2; ++ks) {
            const int c = ks * 4 + (lane >> 4);
            s8v bfrag[NT];
#pragma unroll
            for (int ni = 0; ni < NT; ++ni) {
                const int colr = wc * (NT * 16) + ni * 16 + (lane & 15);
                bfrag[ni] = *(const s8v*)&Bbuf[colr * 64 + (c ^ (colr & 7)) * 8];
            }
#pragma unroll
            for (int mi = 0; mi < 2; ++mi) {
                const int row = wr * 32 + mi * 16 + (lane & 15);
                const s8v af = *(const s8v*)&Abuf[row * 64 + (c ^ (row & 7)) * 8];
#pragma unroll
                for (int ni = 0; ni < NT; ++ni)
                    acc[mi][ni] = __builtin_amdgcn_mfma_f32_16x16x32_bf16(af, bfrag[ni], acc[mi][ni], 0, 0, 0);
            }
        }
        __syncthreads();
    }

#pragma unroll
    for (int mi = 0; mi < 2; ++mi) {
#pragma unroll
        for (int reg = 0; reg < 4; ++reg) {
            const int row = rbase + wr * 32 + mi * 16 + (lane >> 4) * 4 + reg;
            if (row >= M) continue;
            const float rs = SCALE ? rowscale[row] : 1.f;
#pragma unroll
            for (int ni = 0; ni < NT; ++ni) {
                const int col = bn + wc * (NT * 16) + ni * 16 + (lane & 15);
                float v = acc[mi][ni][reg];
                if (SCALE) v *= rs;
                if (bias) v += bias[col];
                if (RELU) v = fmaxf(v, 0.f);
                const size_t oidx = SWZO ? swzidx(row, col, Nout) : ((size_t)row * Nout + col);
                if constexpr (OUTMODE == 2) {
                    Ch[oidx] = f2bf(v);
                } else if constexpr (OUTMODE == 3) {
                    Cf[(size_t)row * Nout + col] = v;
                    Ch[oidx] = f2bf(v);
                } else {
                    Cf[(size_t)row * Nout + col] = v;
                }
            }
        }
    }
}

// ---------------- weight transpose + bf16 convert (chunk-swizzled) ----------
struct WDesc { const float* W; ushort_t* h; int K; int No; };
struct WAll { WDesc d[6]; };

__global__ void wtcvt_kernel(WAll wa) {
    WDesc d = wa.d[blockIdx.y];
    int e = blockIdx.x * blockDim.x + threadIdx.x;
    if (e >= d.K * d.No) return;
    int k = e / d.No, n = e - k * d.No;
    d.h[swzidx(n, k, d.K)] = f2bf(d.W[e]);
}

// ---------------- bucketed CSR build ----------------------------------------
__global__ __launch_bounds__(256) void bcount_kernel(const int* __restrict__ dst,
                                                     int* __restrict__ bcount, int E, int NB) {
    __shared__ int cnt[256];
    const int t = threadIdx.x;
    if (t < NB) cnt[t] = 0;
    __syncthreads();
    for (int e = blockIdx.x * 256 + t; e < E; e += gridDim.x * 256)
        atomicAdd(&cnt[dst[e] >> BSHIFT], 1);
    __syncthreads();
    if (t < NB && cnt[t]) atomicAdd(&bcount[t], cnt[t]);
}

__global__ __launch_bounds__(256) void bscan_kernel(const int* __restrict__ bcount,
                                                    int* __restrict__ bbase,
                                                    int* __restrict__ bcursor, int NB, int E) {
    __shared__ int s[256];
    const int t = threadIdx.x;
    s[t] = (t < NB) ? bcount[t] : 0;
    __syncthreads();
    for (int off = 1; off < 256; off <<= 1) {
        int v = (t >= off) ? s[t - off] : 0;
        __syncthreads();
        s[t] += v;
        __syncthreads();
    }
    int excl = t ? s[t - 1] : 0;
    if (t < NB) { bbase[t] = excl; bcursor[t] = excl; }
    if (t == 0) bbase[NB] = E;
}

__global__ __launch_bounds__(256) void bpart_kernel(const int* __restrict__ src,
                                                    const int* __restrict__ dst,
                                                    int* __restrict__ bcursor,
                                                    unsigned* __restrict__ packed, int E, int NB) {
    __shared__ int cnt[256];
    __shared__ int cur[256];
    const int t = threadIdx.x;
    const int beg = blockIdx.x * 8192;
    const int end = min(beg + 8192, E);
    if (t < NB) cnt[t] = 0;
    __syncthreads();
    for (int e = beg + t; e < end; e += 256) atomicAdd(&cnt[dst[e] >> BSHIFT], 1);
    __syncthreads();
    if (t < NB && cnt[t]) cur[t] = atomicAdd(&bcursor[t], cnt[t]);
    __syncthreads();
    for (int e = beg + t; e < end; e += 256) {
        int d = dst[e];
        int b = d >> BSHIFT;
        int pos = atomicAdd(&cur[b], 1);
        packed[pos] = (unsigned)src[e] | ((unsigned)(d & ((1 << BSHIFT) - 1)) << 16);
    }
}

__global__ __launch_bounds__(256) void bbuild_kernel(const int* __restrict__ bbase,
                                                     const unsigned* __restrict__ packed,
                                                     int* __restrict__ col,
                                                     int* __restrict__ rowstart,
                                                     float* __restrict__ dinv, int N, int E) {
    __shared__ int ncnt[256];
    __shared__ int s[256];
    __shared__ int ncur[256];
    const int b = blockIdx.x;
    const int t = threadIdx.x;
    const int beg = bbase[b], end = bbase[b + 1];
    const int node0 = b << BSHIFT;
    const int nInB = min(256, N - node0);
    ncnt[t] = 0;
    __syncthreads();
    for (int e = beg + t; e < end; e += 256) atomicAdd(&ncnt[packed[e] >> 16], 1);
    __syncthreads();
    s[t] = ncnt[t];
    __syncthreads();
    for (int off = 1; off < 256; off <<= 1) {
        int v = (t >= off) ? s[t - off] : 0;
        __syncthreads();
        s[t] += v;
        __syncthreads();
    }
    int excl = t ? s[t - 1] : 0;
    if (t < nInB) {
        rowstart[node0 + t] = beg + excl;
        dinv[node0 + t] = rsqrtf((float)ncnt[t] + 1.0f);
    }
    ncur[t] = beg + excl;
    __syncthreads();
    for (int e = beg + t; e < end; e += 256) {
        unsigned p = packed[e];
        int pos = atomicAdd(&ncur[p >> 16], 1);
        col[pos] = (int)(p & 0xFFFFu);
    }
    if (b == 0 && t == 0) rowstart[N] = E;
}

// ---------------- feature-sliced CSR gather (F=128, XCD-pinned slices) ------
// Block bid: nodes (bid>>3)*4..+4 (one per wave), slice bid&7 (32B = 2 uint4
// of the 256B row). With round-robin bid%8->XCD, each XCD touches only its
// 1.6MB slice of hws -> L2-resident. 2 lanes/edge, 32 edges per wave-load.
__global__ __launch_bounds__(256) void gathers128_kernel(const int* __restrict__ rowstart,
                                                         const int* __restrict__ col,
                                                         const float* __restrict__ dinv,
                                                         const ushort_t* __restrict__ hws,
                                                         const float* __restrict__ bias,
                                                         ushort_t* __restrict__ aggb, int N) {
    const int slice = blockIdx.x & 7;
    const int nb    = blockIdx.x >> 3;
    const int wave  = threadIdx.x >> 6;
    const int lane  = threadIdx.x & 63;
    const int d = nb * 4 + wave;
    if (d >= N) return;
    const int beg = rowstart[d], end = rowstart[d + 1];
    const float dd = dinv[d];
    const uint4* rowp = (const uint4*)hws;
    const int q  = lane >> 1;          // edge slot 0..31
    const int c2 = lane & 1;           // uint4 within 32B slice
    const int cu = slice * 2 + c2;     // uint4 index within row [0,16)

    float acc[8] = {};
    {
        uint4 sv = rowp[(size_t)d * 16 + cu];
        if (q == 0) add8(acc, sv, 1.f);
    }
    for (int e0 = beg; e0 < end; e0 += 64) {
        int nid = (e0 + lane < end) ? col[e0 + lane] : 0;
        int cnt = min(64, end - e0);
        for (int jj = 0; jj < cnt; jj += 32) {
            int s = __shfl(nid, jj + q);
            float m = (jj + q < cnt) ? 1.f : 0.f;
            uint4 u = rowp[(size_t)s * 16 + cu];
            add8(acc, u, m);
        }
    }
#pragma unroll
    for (int i = 0; i < 8; ++i) {
        acc[i] += __shfl_down(acc[i], 2);
        acc[i] += __shfl_down(acc[i], 4);
        acc[i] += __shfl_down(acc[i], 8);
        acc[i] += __shfl_down(acc[i], 16);
        acc[i] += __shfl_down(acc[i], 32);
    }
    if (q == 0) {                      // lanes 0 (c2=0) and 1 (c2=1)
        f4 b0 = *(const f4*)&bias[cu * 8];
        f4 b1 = *(const f4*)&bias[cu * 8 + 4];
        float r[8];
        r[0] = fmaxf(acc[0] * dd + b0.x, 0.f); r[1] = fmaxf(acc[1] * dd + b0.y, 0.f);
        r[2] = fmaxf(acc[2] * dd + b0.z, 0.f); r[3] = fmaxf(acc[3] * dd + b0.w, 0.f);
        r[4] = fmaxf(acc[4] * dd + b1.x, 0.f); r[5] = fmaxf(acc[5] * dd + b1.y, 0.f);
        r[6] = fmaxf(acc[6] * dd + b1.z, 0.f); r[7] = fmaxf(acc[7] * dd + b1.w, 0.f);
        uint4 o;
        o.x = (unsigned)f2bf(r[0]) | ((unsigned)f2bf(r[1]) << 16);
        o.y = (unsigned)f2bf(r[2]) | ((unsigned)f2bf(r[3]) << 16);
        o.z = (unsigned)f2bf(r[4]) | ((unsigned)f2bf(r[5]) << 16);
        o.w = (unsigned)f2bf(r[6]) | ((unsigned)f2bf(r[7]) << 16);
        const int g2 = cu >> 3;
        const int ch = (cu & 7) ^ (d & 7);
        ((uint4*)aggb)[(size_t)d * 16 + g2 * 8 + ch] = o;
    }
}

// ---------------- wide-row CSR gather (F=64; unchanged from R22) ------------
__global__ __launch_bounds__(256) void gather64_kernel(const int* __restrict__ rowstart,
                                                       const int* __restrict__ col,
                                                       const float* __restrict__ dinv,
                                                       const ushort_t* __restrict__ hws,
                                                       const float* __restrict__ bias,
                                                       ushort_t* __restrict__ aggb, int N) {
    const int wave = threadIdx.x >> 6;
    const int lane = threadIdx.x & 63;
    const int d = blockIdx.x * 4 + wave;
    if (d >= N) return;
    const int beg = rowstart[d], end = rowstart[d + 1];
    const float dd = dinv[d];
    const uint4* rowp = (const uint4*)hws;
    const int q = lane >> 3;          // edge sub-slot 0..7
    const int c = lane & 7;           // uint4 slot within row
    float acc[8] = {};
    uint4 sv = rowp[(size_t)d * 8 + c];
    if (q == 0) add8(acc, sv, 1.f);
    for (int e0 = beg; e0 < end; e0 += 64) {
        int nid = (e0 + lane < end) ? col[e0 + lane] : 0;
        int cnt = min(64, end - e0);
        for (int jj = 0; jj < cnt; jj += 8) {
            int s = __shfl(nid, jj + q);
            float m = (jj + q < cnt) ? 1.f : 0.f;
            uint4 u = rowp[(size_t)s * 8 + c];
            add8(acc, u, m);
        }
    }
#pragma unroll
    for (int i = 0; i < 8; ++i) {
        acc[i] += __shfl_down(acc[i], 32);
        acc[i] += __shfl_down(acc[i], 16);
        acc[i] += __shfl_down(acc[i], 8);
    }
    if (q == 0) {
        f4 b0 = *(const f4*)&bias[c * 8];
        f4 b1 = *(const f4*)&bias[c * 8 + 4];
        float r[8];
        r[0] = fmaxf(acc[0] * dd + b0.x, 0.f); r[1] = fmaxf(acc[1] * dd + b0.y, 0.f);
        r[2] = fmaxf(acc[2] * dd + b0.z, 0.f); r[3] = fmaxf(acc[3] * dd + b0.w, 0.f);
        r[4] = fmaxf(acc[4] * dd + b1.x, 0.f); r[5] = fmaxf(acc[5] * dd + b1.y, 0.f);
        r[6] = fmaxf(acc[6] * dd + b1.z, 0.f); r[7] = fmaxf(acc[7] * dd + b1.w, 0.f);
        uint4 o;
        o.x = (unsigned)f2bf(r[0]) | ((unsigned)f2bf(r[1]) << 16);
        o.y = (unsigned)f2bf(r[2]) | ((unsigned)f2bf(r[3]) << 16);
        o.z = (unsigned)f2bf(r[4]) | ((unsigned)f2bf(r[5]) << 16);
        o.w = (unsigned)f2bf(r[6]) | ((unsigned)f2bf(r[7]) << 16);
        const int ch = c ^ (d & 7);
        ((uint4*)aggb)[(size_t)d * 8 + ch] = o;
    }
}

// ---------------- edge decode: 8 edges per wave, 16B/lane -------------------
__global__ __launch_bounds__(256) void decode8_kernel(const ushort_t* __restrict__ emb1b,
                                                      const int* __restrict__ eli,
                                                      const float* __restrict__ Wpost,
                                                      const float* __restrict__ bpost,
                                                      float* __restrict__ pred, int L) {
    const int wave = threadIdx.x >> 6;
    const int lane = threadIdx.x & 63;
    const int l8 = (blockIdx.x * 4 + wave) * 8;
    if (l8 >= L) return;
    const int q = lane >> 3;
    const int c = lane & 7;
    const int l = min(l8 + q, L - 1);
    const int s = eli[l];
    const int d = eli[L + l];
    const uint4* rowp = (const uint4*)emb1b;
    uint4 ua = rowp[(size_t)s * 8 + c];
    uint4 ub = rowp[(size_t)d * 8 + c];
    f4 w0 = *(const f4*)&Wpost[c * 16];
    f4 w1 = *(const f4*)&Wpost[c * 16 + 4];
    f4 w2 = *(const f4*)&Wpost[c * 16 + 8];
    f4 w3 = *(const f4*)&Wpost[c * 16 + 12];
    float p = 0.f;
    p += __uint_as_float(ua.x << 16) * __uint_as_float(ub.x << 16) * (w0.x + w0.y);
    p += __uint_as_float(ua.x & 0xFFFF0000u) * __uint_as_float(ub.x & 0xFFFF0000u) * (w0.z + w0.w);
    p += __uint_as_float(ua.y << 16) * __uint_as_float(ub.y << 16) * (w1.x + w1.y);
    p += __uint_as_float(ua.y & 0xFFFF0000u) * __uint_as_float(ub.y & 0xFFFF0000u) * (w1.z + w1.w);
    p += __uint_as_float(ua.z << 16) * __uint_as_float(ub.z << 16) * (w2.x + w2.y);
    p += __uint_as_float(ua.z & 0xFFFF0000u) * __uint_as_float(ub.z & 0xFFFF0000u) * (w2.z + w2.w);
    p += __uint_as_float(ua.w << 16) * __uint_as_float(ub.w << 16) * (w3.x + w3.y);
    p += __uint_as_float(ua.w & 0xFFFF0000u) * __uint_as_float(ub.w & 0xFFFF0000u) * (w3.z + w3.w);
    p += __shfl_down(p, 4);
    p += __shfl_down(p, 2);
    p += __shfl_down(p, 1);
    if (c == 0 && l8 + q < L) pred[l8 + q] = p + bpost[0] + bpost[1];
}

// ---------------------------------------------------------------------------
extern "C" void kernel_launch(void* const* d_in, const int* in_sizes, int n_in,
                              void* d_out, int out_size, void* d_ws, size_t ws_size,
                              hipStream_t stream) {
    const float* x     = (const float*)d_in[0];
    const float* prev0 = (const float*)d_in[1];
    const float* prev1 = (const float*)d_in[2];
    const float* Wpre1 = (const float*)d_in[3];
    const float* bpre1 = (const float*)d_in[4];
    const float* Wpre2 = (const float*)d_in[5];
    const float* bpre2 = (const float*)d_in[6];
    const float* Wc1   = (const float*)d_in[7];
    const float* bc1   = (const float*)d_in[8];
    const float* Wc2   = (const float*)d_in[9];
    const float* bc2   = (const float*)d_in[10];
    const float* Wm1   = (const float*)d_in[11];
    const float* bm1   = (const float*)d_in[12];
    const float* Wm2   = (const float*)d_in[13];
    const float* bm2   = (const float*)d_in[14];
    const float* Wpost = (const float*)d_in[15];
    const float* bpost = (const float*)d_in[16];
    const int* edge_index = (const int*)d_in[17];
    const int* eli        = (const int*)d_in[18];

    const int N = in_sizes[0] / 256;   // 50000  (must be <= 65536 for packing)
    const int E = in_sizes[17] / 2;    // 1.6M
    const int L = in_sizes[18] / 2;    // 200K
    const int NB = (N + 255) >> BSHIFT;

    const int* src = edge_index;
    const int* dst = edge_index + E;

    float* out  = (float*)d_out;
    float* pred = out;                        // [L]
    float* emb0 = out + L;                    // [N,128]
    float* emb1 = out + L + (size_t)N * 128;  // [N,64]

    // ---- workspace layout (FLOAT-SLOT offsets; R17/R20 map, verified) ----
    float* ws = (float*)d_ws;
    unsigned* packed = (unsigned*)ws;                      // [0,32N) pre-G1
    ushort_t* h1h   = (ushort_t*)ws;                       // [0,128N) G1->G2 (swz)
    ushort_t* hws1b = (ushort_t*)ws;                       // [0,64N)  G3->gather1 (lin)
    ushort_t* emb0b = (ushort_t*)ws;                       // [0,64N)  G5->G6 (swz)
    ushort_t* emb1b = (ushort_t*)ws;                       // [0,32N)  G8->decode (lin)
    ushort_t* agg1b = (ushort_t*)(ws + (size_t)64 * N);    // [64N,128N) (swz)
    ushort_t* hws2b = (ushort_t*)(ws + (size_t)64 * N);    // [64N,96N) (lin)
    ushort_t* agg2b = (ushort_t*)(ws + (size_t)96 * N);    // [96N,128N) (swz)
    ushort_t* h2b   = (ushort_t*)(ws + (size_t)128 * N);   // [128N,192N) (swz)
    ushort_t* p0b   = (ushort_t*)(ws + (size_t)192 * N);   // [192N,256N) (swz)
    ushort_t* p1b   = (ushort_t*)(ws + (size_t)256 * N);   // [256N,288N) (swz)
    int*      col   = (int*)(ws + (size_t)288 * N);        // [288N,320N)

    size_t o = (size_t)320 * N;
    int* rowstart = (int*)(ws + o);         o += ((size_t)N + 4) & ~(size_t)3;
    float* dinv = ws + o;                   o += ((size_t)N + 3) & ~(size_t)3;
    int* bbase = (int*)(ws + o);            o += 260;
    int* bcursor = (int*)(ws + o);          o += 260;
    int* bcount = (int*)(ws + o);           o += 260;
    ushort_t* wb = (ushort_t*)(ws + o);     // 163840 ushorts (16B-aligned)

    ushort_t* wpre1t = wb + 0;        // [256][256] swz
    ushort_t* wpre2t = wb + 65536;    // [128][256] swz
    ushort_t* wc1t   = wb + 98304;    // [128][128] swz
    ushort_t* wm1t   = wb + 114688;   // [128][256] swz
    ushort_t* wc2t   = wb + 147456;   // [64][128] swz
    ushort_t* wm2t   = wb + 155648;   // [64][128] swz

    // 0) prev0/prev1 -> bf16 (swizzled)
    {
        size_t n0 = (size_t)N * 128, n1 = (size_t)N * 64;
        f2bswz_kernel<128><<<(int)((n0 / 8 + 255) / 256), 256, 0, stream>>>(prev0, p0b, n0);
        f2bswz_kernel<64><<<(int)((n1 / 8 + 255) / 256), 256, 0, stream>>>(prev1, p1b, n1);
    }

    // 0a) bucketed CSR build + dinv
    hipMemsetAsync(bcount, 0, (size_t)NB * sizeof(int), stream);
    bcount_kernel<<<1024, 256, 0, stream>>>(dst, bcount, E, NB);
    bscan_kernel<<<1, 256, 0, stream>>>(bcount, bbase, bcursor, NB, E);
    bpart_kernel<<<(E + 8191) / 8192, 256, 0, stream>>>(src, dst, bcursor, packed, E, NB);
    bbuild_kernel<<<NB, 256, 0, stream>>>(bbase, packed, col, rowstart, dinv, N, E);

    // 0b) weights: transpose + bf16 convert, chunk-swizzled [Nout][K]
    WAll wa;
    wa.d[0] = {Wpre1, wpre1t, 256, 256};
    wa.d[1] = {Wpre2, wpre2t, 256, 128};
    wa.d[2] = {Wc1,   wc1t,   128, 128};
    wa.d[3] = {Wm1,   wm1t,   256, 128};
    wa.d[4] = {Wc2,   wc2t,   128, 64};
    wa.d[5] = {Wm2,   wm2t,   128, 64};
    wtcvt_kernel<<<dim3(256, 6), 256, 0, stream>>>(wa);

    const int gy = (N + 63) / 64;   // 782 row blocks

    // 1) h1 = bf16(relu(x@Wpre1+b))           [N,256]  K=256, fp32 A
    gemm_lds<128, 256, 256, true, true, false, false, 2, true><<<dim3(2, gy), 256, 0, stream>>>(
        x, nullptr, nullptr, wpre1t, bpre1, nullptr, nullptr, h1h, N, 256);
    // 2) h2 = bf16(relu(h1@Wpre2+b))          [N,128]  K=256, DMA
    gemm_lds<128, 256, 256, false, true, false, false, 2, true><<<dim3(1, gy), 256, 0, stream>>>(
        nullptr, h1h, nullptr, wpre2t, bpre2, nullptr, nullptr, h2b, N, 128);
    // 3) hws1 = bf16((h2@Wc1)*dinv[row])      [N,128]  K=128  (linear out)
    gemm_lds<128, 128, 128, false, false, true, false, 2, false><<<dim3(1, gy), 256, 0, stream>>>(
        nullptr, h2b, nullptr, wc1t, nullptr, dinv, nullptr, hws1b, N, 128);
    // 4) agg1 = bf16(relu(dinv*(hws1[d]+sum hws1[s])+bc1))  (sliced, XCD-pinned)
    gathers128_kernel<<<((N + 3) / 4) * 8, 256, 0, stream>>>(rowstart, col, dinv, hws1b, bc1, agg1b, N);
    // 5) emb0 = [agg1,prev0]@Wm1+bm1 (fp32 + swz bf16 copy)  [N,128]  K=128+128
    gemm_lds<128, 256, 128, false, false, false, true, 3, true><<<dim3(1, gy), 256, 0, stream>>>(
        nullptr, agg1b, p0b, wm1t, bm1, nullptr, emb0, emb0b, N, 128);
    // 6) hws2 = bf16((emb0@Wc2)*dinv[row])    [N,64]   K=128  (linear out)
    gemm_lds<64, 128, 128, false, false, true, false, 2, false><<<dim3(1, gy), 256, 0, stream>>>(
        nullptr, emb0b, nullptr, wc2t, nullptr, dinv, nullptr, hws2b, N, 64);
    // 7) agg2 = bf16(relu(dinv*(hws2[d]+sum hws2[s])+bc2))
    gather64_kernel<<<(N + 3) / 4, 256, 0, stream>>>(rowstart, col, dinv, hws2b, bc2, agg2b, N);
    // 8) emb1 = [agg2,prev1]@Wm2+bm2 (fp32 + linear bf16 copy)  [N,64]  K=64+64
    gemm_lds<64, 128, 64, false, false, false, true, 3, false><<<dim3(1, gy), 256, 0, stream>>>(
        nullptr, agg2b, p1b, wm2t, bm2, nullptr, emb1, emb1b, N, 64);
    // 9) decode: 8 edges per wave
    decode8_kernel<<<(L + 31) / 32, 256, 0, stream>>>(emb1b, eli, Wpost, bpost, pred, L);
}

// Round 26
// 288.533 us; speedup vs baseline: 1.4237x; 1.4237x over previous
//
#include <hip/hip_runtime.h>
#include <hip/hip_bf16.h>

// ---------------------------------------------------------------------------
// ROLAND-style GNN forward. Round 25: revert to the best-measured config
// (R22, 288us). R23-R25 falsified three gather theories: deeper reg ILP
// (compiler-flattened), DMA pipelining (LDS round-trip overhead > gain),
// feature slicing (line-granularity + col re-read blew traffic to 365MB).
// gather4 at 51us sits within ~1.5x of its compulsory L3 floor (102MB).
// Structure: BM=64 single-buffered swizzled DMA-LDS GEMMs (bf16 weights,
// bf16 activations), wide-row gathers (4/8 edges per wave-load), bucketed
// CSR build, 8-edge decode.
// ---------------------------------------------------------------------------

typedef unsigned short ushort_t;
typedef __attribute__((ext_vector_type(8))) short s8v;   // 8 bf16 (4 VGPRs)
typedef __attribute__((ext_vector_type(4))) float f4;    // MFMA accumulator

#define BSHIFT 8                       // nodes per bucket = 256 (N<=65536)

__device__ __forceinline__ ushort_t f2bf(float v) {
    unsigned u = __float_as_uint(v);
    return (ushort_t)((u + 0x7FFFu + ((u >> 16) & 1u)) >> 16);
}

__device__ __forceinline__ s8v cvt8(f4 v0, f4 v1) {
    ushort_t hb[8];
    hb[0] = f2bf(v0.x); hb[1] = f2bf(v0.y); hb[2] = f2bf(v0.z); hb[3] = f2bf(v0.w);
    hb[4] = f2bf(v1.x); hb[5] = f2bf(v1.y); hb[6] = f2bf(v1.z); hb[7] = f2bf(v1.w);
    return *(s8v*)hb;
}

// swizzled ushort index within a row of width Wd: chunk c=(k&63)>>3 XOR row&7
__device__ __forceinline__ size_t swzidx(int row, int k, int Wd) {
    int p = (((k & 63) >> 3) ^ (row & 7));
    return (size_t)row * Wd + (k & ~63) + p * 8 + (k & 7);
}

// async 16B/lane global->LDS DMA; lds base must be wave-uniform
__device__ __forceinline__ void dma16(const ushort_t* g, ushort_t* l) {
    __builtin_amdgcn_global_load_lds(
        (const __attribute__((address_space(1))) unsigned int*)g,
        (__attribute__((address_space(3))) unsigned int*)l, 16, 0, 0);
}

// acc[8] += m * unpack8(uint4 of packed bf16 pairs)
__device__ __forceinline__ void add8(float* acc, uint4 u, float m) {
    acc[0] = fmaf(__uint_as_float(u.x << 16), m, acc[0]);
    acc[1] = fmaf(__uint_as_float(u.x & 0xFFFF0000u), m, acc[1]);
    acc[2] = fmaf(__uint_as_float(u.y << 16), m, acc[2]);
    acc[3] = fmaf(__uint_as_float(u.y & 0xFFFF0000u), m, acc[3]);
    acc[4] = fmaf(__uint_as_float(u.z << 16), m, acc[4]);
    acc[5] = fmaf(__uint_as_float(u.z & 0xFFFF0000u), m, acc[5]);
    acc[6] = fmaf(__uint_as_float(u.w << 16), m, acc[6]);
    acc[7] = fmaf(__uint_as_float(u.w & 0xFFFF0000u), m, acc[7]);
}

// ---------------- fp32 -> bf16 bulk convert (swizzled rows of width W) ------
template <int W>
__global__ __launch_bounds__(256) void f2bswz_kernel(const float* __restrict__ in,
                                                     ushort_t* __restrict__ out, size_t n) {
    size_t i = ((size_t)blockIdx.x * 256 + threadIdx.x) * 8;
    if (i + 8 > n) return;
    f4 v0 = *(const f4*)&in[i];
    f4 v1 = *(const f4*)&in[i + 4];
    int row = (int)(i / W), k = (int)(i % W);
    *(s8v*)&out[swzidx(row, k, W)] = cvt8(v0, v1);
}

// ---------------- LDS-staged MFMA GEMM (BM=64, single-buffer + swizzle) -----
template <int BN, int KW, int K1, bool A1F32, bool RELU, bool SCALE, bool DUAL,
          int OUTMODE, bool SWZO>
__global__ __launch_bounds__(256, 2) void gemm_lds(
    const float* __restrict__ A1f, const ushort_t* __restrict__ A1h,
    const ushort_t* __restrict__ A2h,
    const ushort_t* __restrict__ Wt,
    const float* __restrict__ bias, const float* __restrict__ rowscale,
    float* __restrict__ Cf, ushort_t* __restrict__ Ch,
    int M, int Nout)
{
    constexpr int NT = BN / 32;
    constexpr int K2 = KW - K1;
    __shared__ ushort_t Abuf[64 * 64];       // 8 KB
    __shared__ ushort_t Bbuf[BN * 64];       // 16/8 KB

    const int tid  = threadIdx.x;
    const int lane = tid & 63;
    const int w    = tid >> 6;
    const int wr   = w >> 1, wc = w & 1;
    const int rbase = blockIdx.y * 64;
    const int bn    = blockIdx.x * BN;

    f4 acc[2][NT];
    const f4 zero = {0.f, 0.f, 0.f, 0.f};
#pragma unroll
    for (int mi = 0; mi < 2; ++mi)
#pragma unroll
        for (int ni = 0; ni < NT; ++ni) acc[mi][ni] = zero;

    for (int kt = 0; kt < KW; kt += 64) {
        if constexpr (A1F32) {
#pragma unroll
            for (int j = 0; j < 2; ++j) {
                const int c2 = tid + j * 256;          // 0..511
                const int row = c2 >> 3, c = c2 & 7;
                const int gr = min(rbase + row, M - 1);
                const float* p = &A1f[(size_t)gr * K1 + kt + c * 8];
                const int pc = c ^ (row & 7);
                *(s8v*)&Abuf[row * 64 + pc * 8] = cvt8(*(const f4*)p, *(const f4*)(p + 4));
            }
        } else {
#pragma unroll
            for (int i = 0; i < 2; ++i) {
                const int s = w * 2 + i;               // 1KB slab (8 rows)
                const int row = s * 8 + (lane >> 3);
                const int c = lane & 7;
                const int gr = min(rbase + row, M - 1);
                const ushort_t* g;
                if (DUAL && kt >= K1) g = &A2h[(size_t)gr * K2 + (kt - K1) + c * 8];
                else                  g = &A1h[(size_t)gr * K1 + kt + c * 8];
                dma16(g, &Abuf[s * 512]);
            }
        }
#pragma unroll
        for (int i = 0; i < NT; ++i) {
            const int s = w * NT + i;                  // 1KB slab (8 cols)
            const int colr = s * 8 + (lane >> 3);
            const int c = lane & 7;
            dma16(&Wt[(size_t)(bn + colr) * KW + kt + c * 8], &Bbuf[s * 512]);
        }
        __syncthreads();
#pragma unroll
        for (int ks = 0; ks < 2; ++ks) {
            const int c = ks * 4 + (lane >> 4);
            s8v bfrag[NT];
#pragma unroll
            for (int ni = 0; ni < NT; ++ni) {
                const int colr = wc * (NT * 16) + ni * 16 + (lane & 15);
                bfrag[ni] = *(const s8v*)&Bbuf[colr * 64 + (c ^ (colr & 7)) * 8];
            }
#pragma unroll
            for (int mi = 0; mi < 2; ++mi) {
                const int row = wr * 32 + mi * 16 + (lane & 15);
                const s8v af = *(const s8v*)&Abuf[row * 64 + (c ^ (row & 7)) * 8];
#pragma unroll
                for (int ni = 0; ni < NT; ++ni)
                    acc[mi][ni] = __builtin_amdgcn_mfma_f32_16x16x32_bf16(af, bfrag[ni], acc[mi][ni], 0, 0, 0);
            }
        }
        __syncthreads();
    }

#pragma unroll
    for (int mi = 0; mi < 2; ++mi) {
#pragma unroll
        for (int reg = 0; reg < 4; ++reg) {
            const int row = rbase + wr * 32 + mi * 16 + (lane >> 4) * 4 + reg;
            if (row >= M) continue;
            const float rs = SCALE ? rowscale[row] : 1.f;
#pragma unroll
            for (int ni = 0; ni < NT; ++ni) {
                const int col = bn + wc * (NT * 16) + ni * 16 + (lane & 15);
                float v = acc[mi][ni][reg];
                if (SCALE) v *= rs;
                if (bias) v += bias[col];
                if (RELU) v = fmaxf(v, 0.f);
                const size_t oidx = SWZO ? swzidx(row, col, Nout) : ((size_t)row * Nout + col);
                if constexpr (OUTMODE == 2) {
                    Ch[oidx] = f2bf(v);
                } else if constexpr (OUTMODE == 3) {
                    Cf[(size_t)row * Nout + col] = v;
                    Ch[oidx] = f2bf(v);
                } else {
                    Cf[(size_t)row * Nout + col] = v;
                }
            }
        }
    }
}

// ---------------- weight transpose + bf16 convert (chunk-swizzled) ----------
struct WDesc { const float* W; ushort_t* h; int K; int No; };
struct WAll { WDesc d[6]; };

__global__ void wtcvt_kernel(WAll wa) {
    WDesc d = wa.d[blockIdx.y];
    int e = blockIdx.x * blockDim.x + threadIdx.x;
    if (e >= d.K * d.No) return;
    int k = e / d.No, n = e - k * d.No;
    d.h[swzidx(n, k, d.K)] = f2bf(d.W[e]);
}

// ---------------- bucketed CSR build ----------------------------------------
__global__ __launch_bounds__(256) void bcount_kernel(const int* __restrict__ dst,
                                                     int* __restrict__ bcount, int E, int NB) {
    __shared__ int cnt[256];
    const int t = threadIdx.x;
    if (t < NB) cnt[t] = 0;
    __syncthreads();
    for (int e = blockIdx.x * 256 + t; e < E; e += gridDim.x * 256)
        atomicAdd(&cnt[dst[e] >> BSHIFT], 1);
    __syncthreads();
    if (t < NB && cnt[t]) atomicAdd(&bcount[t], cnt[t]);
}

__global__ __launch_bounds__(256) void bscan_kernel(const int* __restrict__ bcount,
                                                    int* __restrict__ bbase,
                                                    int* __restrict__ bcursor, int NB, int E) {
    __shared__ int s[256];
    const int t = threadIdx.x;
    s[t] = (t < NB) ? bcount[t] : 0;
    __syncthreads();
    for (int off = 1; off < 256; off <<= 1) {
        int v = (t >= off) ? s[t - off] : 0;
        __syncthreads();
        s[t] += v;
        __syncthreads();
    }
    int excl = t ? s[t - 1] : 0;
    if (t < NB) { bbase[t] = excl; bcursor[t] = excl; }
    if (t == 0) bbase[NB] = E;
}

__global__ __launch_bounds__(256) void bpart_kernel(const int* __restrict__ src,
                                                    const int* __restrict__ dst,
                                                    int* __restrict__ bcursor,
                                                    unsigned* __restrict__ packed, int E, int NB) {
    __shared__ int cnt[256];
    __shared__ int cur[256];
    const int t = threadIdx.x;
    const int beg = blockIdx.x * 8192;
    const int end = min(beg + 8192, E);
    if (t < NB) cnt[t] = 0;
    __syncthreads();
    for (int e = beg + t; e < end; e += 256) atomicAdd(&cnt[dst[e] >> BSHIFT], 1);
    __syncthreads();
    if (t < NB && cnt[t]) cur[t] = atomicAdd(&bcursor[t], cnt[t]);
    __syncthreads();
    for (int e = beg + t; e < end; e += 256) {
        int d = dst[e];
        int b = d >> BSHIFT;
        int pos = atomicAdd(&cur[b], 1);
        packed[pos] = (unsigned)src[e] | ((unsigned)(d & ((1 << BSHIFT) - 1)) << 16);
    }
}

__global__ __launch_bounds__(256) void bbuild_kernel(const int* __restrict__ bbase,
                                                     const unsigned* __restrict__ packed,
                                                     int* __restrict__ col,
                                                     int* __restrict__ rowstart,
                                                     float* __restrict__ dinv, int N, int E) {
    __shared__ int ncnt[256];
    __shared__ int s[256];
    __shared__ int ncur[256];
    const int b = blockIdx.x;
    const int t = threadIdx.x;
    const int beg = bbase[b], end = bbase[b + 1];
    const int node0 = b << BSHIFT;
    const int nInB = min(256, N - node0);
    ncnt[t] = 0;
    __syncthreads();
    for (int e = beg + t; e < end; e += 256) atomicAdd(&ncnt[packed[e] >> 16], 1);
    __syncthreads();
    s[t] = ncnt[t];
    __syncthreads();
    for (int off = 1; off < 256; off <<= 1) {
        int v = (t >= off) ? s[t - off] : 0;
        __syncthreads();
        s[t] += v;
        __syncthreads();
    }
    int excl = t ? s[t - 1] : 0;
    if (t < nInB) {
        rowstart[node0 + t] = beg + excl;
        dinv[node0 + t] = rsqrtf((float)ncnt[t] + 1.0f);
    }
    ncur[t] = beg + excl;
    __syncthreads();
    for (int e = beg + t; e < end; e += 256) {
        unsigned p = packed[e];
        int pos = atomicAdd(&ncur[p >> 16], 1);
        col[pos] = (int)(p & 0xFFFFu);
    }
    if (b == 0 && t == 0) rowstart[N] = E;
}

// ---------------- wide-row CSR gather ---------------------------------------
// F=128: quarter-wave (16 lanes) reads one 256B row as uint4 -> 4 edges per
// wave-load. F=64: 8-lane groups -> 8 edges per load. Output swizzled.
template <int F>
__global__ __launch_bounds__(256) void gather4_kernel(const int* __restrict__ rowstart,
                                                      const int* __restrict__ col,
                                                      const float* __restrict__ dinv,
                                                      const ushort_t* __restrict__ hws,
                                                      const float* __restrict__ bias,
                                                      ushort_t* __restrict__ aggb, int N) {
    const int wave = threadIdx.x >> 6;
    const int lane = threadIdx.x & 63;
    const int d = blockIdx.x * 4 + wave;
    if (d >= N) return;
    const int beg = rowstart[d], end = rowstart[d + 1];
    const float dd = dinv[d];
    const uint4* rowp = (const uint4*)hws;

    if (F == 128) {
        const int q = lane >> 4;          // edge sub-slot 0..3
        const int c = lane & 15;          // uint4 slot within row
        float acc[8] = {};
        uint4 sv = rowp[(size_t)d * 16 + c];
        if (q == 0) add8(acc, sv, 1.f);
        for (int e0 = beg; e0 < end; e0 += 64) {
            int nid = (e0 + lane < end) ? col[e0 + lane] : 0;
            int cnt = min(64, end - e0);
            for (int jj = 0; jj < cnt; jj += 4) {
                int s = __shfl(nid, jj + q);
                float m = (jj + q < cnt) ? 1.f : 0.f;
                uint4 u = rowp[(size_t)s * 16 + c];
                add8(acc, u, m);
            }
        }
#pragma unroll
        for (int i = 0; i < 8; ++i) {
            acc[i] += __shfl_down(acc[i], 32);
            acc[i] += __shfl_down(acc[i], 16);
        }
        if (q == 0) {
            f4 b0 = *(const f4*)&bias[c * 8];
            f4 b1 = *(const f4*)&bias[c * 8 + 4];
            float r[8];
            r[0] = fmaxf(acc[0] * dd + b0.x, 0.f); r[1] = fmaxf(acc[1] * dd + b0.y, 0.f);
            r[2] = fmaxf(acc[2] * dd + b0.z, 0.f); r[3] = fmaxf(acc[3] * dd + b0.w, 0.f);
            r[4] = fmaxf(acc[4] * dd + b1.x, 0.f); r[5] = fmaxf(acc[5] * dd + b1.y, 0.f);
            r[6] = fmaxf(acc[6] * dd + b1.z, 0.f); r[7] = fmaxf(acc[7] * dd + b1.w, 0.f);
            uint4 o;
            o.x = (unsigned)f2bf(r[0]) | ((unsigned)f2bf(r[1]) << 16);
            o.y = (unsigned)f2bf(r[2]) | ((unsigned)f2bf(r[3]) << 16);
            o.z = (unsigned)f2bf(r[4]) | ((unsigned)f2bf(r[5]) << 16);
            o.w = (unsigned)f2bf(r[6]) | ((unsigned)f2bf(r[7]) << 16);
            const int g = c >> 3;
            const int ch = (c & 7) ^ (d & 7);
            ((uint4*)aggb)[(size_t)d * 16 + g * 8 + ch] = o;
        }
    } else {  // F == 64: 8 uint4 per row, 8 lanes per row
        const int q = lane >> 3;          // edge sub-slot 0..7
        const int c = lane & 7;           // uint4 slot within row
        float acc[8] = {};
        uint4 sv = rowp[(size_t)d * 8 + c];
        if (q == 0) add8(acc, sv, 1.f);
        for (int e0 = beg; e0 < end; e0 += 64) {
            int nid = (e0 + lane < end) ? col[e0 + lane] : 0;
            int cnt = min(64, end - e0);
            for (int jj = 0; jj < cnt; jj += 8) {
                int s = __shfl(nid, jj + q);
                float m = (jj + q < cnt) ? 1.f : 0.f;
                uint4 u = rowp[(size_t)s * 8 + c];
                add8(acc, u, m);
            }
        }
#pragma unroll
        for (int i = 0; i < 8; ++i) {
            acc[i] += __shfl_down(acc[i], 32);
            acc[i] += __shfl_down(acc[i], 16);
            acc[i] += __shfl_down(acc[i], 8);
        }
        if (q == 0) {
            f4 b0 = *(const f4*)&bias[c * 8];
            f4 b1 = *(const f4*)&bias[c * 8 + 4];
            float r[8];
            r[0] = fmaxf(acc[0] * dd + b0.x, 0.f); r[1] = fmaxf(acc[1] * dd + b0.y, 0.f);
            r[2] = fmaxf(acc[2] * dd + b0.z, 0.f); r[3] = fmaxf(acc[3] * dd + b0.w, 0.f);
            r[4] = fmaxf(acc[4] * dd + b1.x, 0.f); r[5] = fmaxf(acc[5] * dd + b1.y, 0.f);
            r[6] = fmaxf(acc[6] * dd + b1.z, 0.f); r[7] = fmaxf(acc[7] * dd + b1.w, 0.f);
            uint4 o;
            o.x = (unsigned)f2bf(r[0]) | ((unsigned)f2bf(r[1]) << 16);
            o.y = (unsigned)f2bf(r[2]) | ((unsigned)f2bf(r[3]) << 16);
            o.z = (unsigned)f2bf(r[4]) | ((unsigned)f2bf(r[5]) << 16);
            o.w = (unsigned)f2bf(r[6]) | ((unsigned)f2bf(r[7]) << 16);
            const int ch = c ^ (d & 7);
            ((uint4*)aggb)[(size_t)d * 8 + ch] = o;
        }
    }
}

// ---------------- edge decode: 8 edges per wave, 16B/lane -------------------
__global__ __launch_bounds__(256) void decode8_kernel(const ushort_t* __restrict__ emb1b,
                                                      const int* __restrict__ eli,
                                                      const float* __restrict__ Wpost,
                                                      const float* __restrict__ bpost,
                                                      float* __restrict__ pred, int L) {
    const int wave = threadIdx.x >> 6;
    const int lane = threadIdx.x & 63;
    const int l8 = (blockIdx.x * 4 + wave) * 8;
    if (l8 >= L) return;
    const int q = lane >> 3;
    const int c = lane & 7;
    const int l = min(l8 + q, L - 1);
    const int s = eli[l];
    const int d = eli[L + l];
    const uint4* rowp = (const uint4*)emb1b;
    uint4 ua = rowp[(size_t)s * 8 + c];
    uint4 ub = rowp[(size_t)d * 8 + c];
    f4 w0 = *(const f4*)&Wpost[c * 16];
    f4 w1 = *(const f4*)&Wpost[c * 16 + 4];
    f4 w2 = *(const f4*)&Wpost[c * 16 + 8];
    f4 w3 = *(const f4*)&Wpost[c * 16 + 12];
    float p = 0.f;
    p += __uint_as_float(ua.x << 16) * __uint_as_float(ub.x << 16) * (w0.x + w0.y);
    p += __uint_as_float(ua.x & 0xFFFF0000u) * __uint_as_float(ub.x & 0xFFFF0000u) * (w0.z + w0.w);
    p += __uint_as_float(ua.y << 16) * __uint_as_float(ub.y << 16) * (w1.x + w1.y);
    p += __uint_as_float(ua.y & 0xFFFF0000u) * __uint_as_float(ub.y & 0xFFFF0000u) * (w1.z + w1.w);
    p += __uint_as_float(ua.z << 16) * __uint_as_float(ub.z << 16) * (w2.x + w2.y);
    p += __uint_as_float(ua.z & 0xFFFF0000u) * __uint_as_float(ub.z & 0xFFFF0000u) * (w2.z + w2.w);
    p += __uint_as_float(ua.w << 16) * __uint_as_float(ub.w << 16) * (w3.x + w3.y);
    p += __uint_as_float(ua.w & 0xFFFF0000u) * __uint_as_float(ub.w & 0xFFFF0000u) * (w3.z + w3.w);
    p += __shfl_down(p, 4);
    p += __shfl_down(p, 2);
    p += __shfl_down(p, 1);
    if (c == 0 && l8 + q < L) pred[l8 + q] = p + bpost[0] + bpost[1];
}

// ---------------------------------------------------------------------------
extern "C" void kernel_launch(void* const* d_in, const int* in_sizes, int n_in,
                              void* d_out, int out_size, void* d_ws, size_t ws_size,
                              hipStream_t stream) {
    const float* x     = (const float*)d_in[0];
    const float* prev0 = (const float*)d_in[1];
    const float* prev1 = (const float*)d_in[2];
    const float* Wpre1 = (const float*)d_in[3];
    const float* bpre1 = (const float*)d_in[4];
    const float* Wpre2 = (const float*)d_in[5];
    const float* bpre2 = (const float*)d_in[6];
    const float* Wc1   = (const float*)d_in[7];
    const float* bc1   = (const float*)d_in[8];
    const float* Wc2   = (const float*)d_in[9];
    const float* bc2   = (const float*)d_in[10];
    const float* Wm1   = (const float*)d_in[11];
    const float* bm1   = (const float*)d_in[12];
    const float* Wm2   = (const float*)d_in[13];
    const float* bm2   = (const float*)d_in[14];
    const float* Wpost = (const float*)d_in[15];
    const float* bpost = (const float*)d_in[16];
    const int* edge_index = (const int*)d_in[17];
    const int* eli        = (const int*)d_in[18];

    const int N = in_sizes[0] / 256;   // 50000  (must be <= 65536 for packing)
    const int E = in_sizes[17] / 2;    // 1.6M
    const int L = in_sizes[18] / 2;    // 200K
    const int NB = (N + 255) >> BSHIFT;

    const int* src = edge_index;
    const int* dst = edge_index + E;

    float* out  = (float*)d_out;
    float* pred = out;                        // [L]
    float* emb0 = out + L;                    // [N,128]
    float* emb1 = out + L + (size_t)N * 128;  // [N,64]

    // ---- workspace layout (FLOAT-SLOT offsets; R17/R20 map, verified) ----
    float* ws = (float*)d_ws;
    unsigned* packed = (unsigned*)ws;                      // [0,32N) pre-G1
    ushort_t* h1h   = (ushort_t*)ws;                       // [0,128N) G1->G2 (swz)
    ushort_t* hws1b = (ushort_t*)ws;                       // [0,64N)  G3->gather1 (lin)
    ushort_t* emb0b = (ushort_t*)ws;                       // [0,64N)  G5->G6 (swz)
    ushort_t* emb1b = (ushort_t*)ws;                       // [0,32N)  G8->decode (lin)
    ushort_t* agg1b = (ushort_t*)(ws + (size_t)64 * N);    // [64N,128N) (swz)
    ushort_t* hws2b = (ushort_t*)(ws + (size_t)64 * N);    // [64N,96N) (lin)
    ushort_t* agg2b = (ushort_t*)(ws + (size_t)96 * N);    // [96N,128N) (swz)
    ushort_t* h2b   = (ushort_t*)(ws + (size_t)128 * N);   // [128N,192N) (swz)
    ushort_t* p0b   = (ushort_t*)(ws + (size_t)192 * N);   // [192N,256N) (swz)
    ushort_t* p1b   = (ushort_t*)(ws + (size_t)256 * N);   // [256N,288N) (swz)
    int*      col   = (int*)(ws + (size_t)288 * N);        // [288N,320N)

    size_t o = (size_t)320 * N;
    int* rowstart = (int*)(ws + o);         o += ((size_t)N + 4) & ~(size_t)3;
    float* dinv = ws + o;                   o += ((size_t)N + 3) & ~(size_t)3;
    int* bbase = (int*)(ws + o);            o += 260;
    int* bcursor = (int*)(ws + o);          o += 260;
    int* bcount = (int*)(ws + o);           o += 260;
    ushort_t* wb = (ushort_t*)(ws + o);     // 163840 ushorts (16B-aligned)

    ushort_t* wpre1t = wb + 0;        // [256][256] swz
    ushort_t* wpre2t = wb + 65536;    // [128][256] swz
    ushort_t* wc1t   = wb + 98304;    // [128][128] swz
    ushort_t* wm1t   = wb + 114688;   // [128][256] swz
    ushort_t* wc2t   = wb + 147456;   // [64][128] swz
    ushort_t* wm2t   = wb + 155648;   // [64][128] swz

    // 0) prev0/prev1 -> bf16 (swizzled)
    {
        size_t n0 = (size_t)N * 128, n1 = (size_t)N * 64;
        f2bswz_kernel<128><<<(int)((n0 / 8 + 255) / 256), 256, 0, stream>>>(prev0, p0b, n0);
        f2bswz_kernel<64><<<(int)((n1 / 8 + 255) / 256), 256, 0, stream>>>(prev1, p1b, n1);
    }

    // 0a) bucketed CSR build + dinv
    hipMemsetAsync(bcount, 0, (size_t)NB * sizeof(int), stream);
    bcount_kernel<<<1024, 256, 0, stream>>>(dst, bcount, E, NB);
    bscan_kernel<<<1, 256, 0, stream>>>(bcount, bbase, bcursor, NB, E);
    bpart_kernel<<<(E + 8191) / 8192, 256, 0, stream>>>(src, dst, bcursor, packed, E, NB);
    bbuild_kernel<<<NB, 256, 0, stream>>>(bbase, packed, col, rowstart, dinv, N, E);

    // 0b) weights: transpose + bf16 convert, chunk-swizzled [Nout][K]
    WAll wa;
    wa.d[0] = {Wpre1, wpre1t, 256, 256};
    wa.d[1] = {Wpre2, wpre2t, 256, 128};
    wa.d[2] = {Wc1,   wc1t,   128, 128};
    wa.d[3] = {Wm1,   wm1t,   256, 128};
    wa.d[4] = {Wc2,   wc2t,   128, 64};
    wa.d[5] = {Wm2,   wm2t,   128, 64};
    wtcvt_kernel<<<dim3(256, 6), 256, 0, stream>>>(wa);

    const int gy = (N + 63) / 64;   // 782 row blocks

    // 1) h1 = bf16(relu(x@Wpre1+b))           [N,256]  K=256, fp32 A
    gemm_lds<128, 256, 256, true, true, false, false, 2, true><<<dim3(2, gy), 256, 0, stream>>>(
        x, nullptr, nullptr, wpre1t, bpre1, nullptr, nullptr, h1h, N, 256);
    // 2) h2 = bf16(relu(h1@Wpre2+b))          [N,128]  K=256, DMA
    gemm_lds<128, 256, 256, false, true, false, false, 2, true><<<dim3(1, gy), 256, 0, stream>>>(
        nullptr, h1h, nullptr, wpre2t, bpre2, nullptr, nullptr, h2b, N, 128);
    // 3) hws1 = bf16((h2@Wc1)*dinv[row])      [N,128]  K=128  (linear out)
    gemm_lds<128, 128, 128, false, false, true, false, 2, false><<<dim3(1, gy), 256, 0, stream>>>(
        nullptr, h2b, nullptr, wc1t, nullptr, dinv, nullptr, hws1b, N, 128);
    // 4) agg1 = bf16(relu(dinv*(hws1[d]+sum hws1[s])+bc1))  (swizzled out)
    gather4_kernel<128><<<(N + 3) / 4, 256, 0, stream>>>(rowstart, col, dinv, hws1b, bc1, agg1b, N);
    // 5) emb0 = [agg1,prev0]@Wm1+bm1 (fp32 + swz bf16 copy)  [N,128]  K=128+128
    gemm_lds<128, 256, 128, false, false, false, true, 3, true><<<dim3(1, gy), 256, 0, stream>>>(
        nullptr, agg1b, p0b, wm1t, bm1, nullptr, emb0, emb0b, N, 128);
    // 6) hws2 = bf16((emb0@Wc2)*dinv[row])    [N,64]   K=128  (linear out)
    gemm_lds<64, 128, 128, false, false, true, false, 2, false><<<dim3(1, gy), 256, 0, stream>>>(
        nullptr, emb0b, nullptr, wc2t, nullptr, dinv, nullptr, hws2b, N, 64);
    // 7) agg2 = bf16(relu(dinv*(hws2[d]+sum hws2[s])+bc2))  (swizzled out)
    gather4_kernel<64><<<(N + 3) / 4, 256, 0, stream>>>(rowstart, col, dinv, hws2b, bc2, agg2b, N);
    // 8) emb1 = [agg2,prev1]@Wm2+bm2 (fp32 + linear bf16 copy)  [N,64]  K=64+64
    gemm_lds<64, 128, 64, false, false, false, true, 3, false><<<dim3(1, gy), 256, 0, stream>>>(
        nullptr, agg2b, p1b, wm2t, bm2, nullptr, emb1, emb1b, N, 64);
    // 9) decode: 8 edges per wave
    decode8_kernel<<<(L + 31) / 32, 256, 0, stream>>>(emb1b, eli, Wpost, bpost, pred, L);
}

// Round 27
// 281.354 us; speedup vs baseline: 1.4600x; 1.0255x over previous
//
#include <hip/hip_runtime.h>
#include <hip/hip_bf16.h>

// ---------------------------------------------------------------------------
// ROLAND-style GNN forward. Round 26: fp8 gather operands. hws1/hws2 are
// stored as OCP e4m3 (hardware v_cvt_pk_fp8_f32 in the G3/G6 epilogue),
// halving the gather's random-row traffic (the measured 3.25 TB/s L3
// service is the session-stable wall; bytes are the only lever left).
// Decode in-gather via v_cvt_pk_f32_fp8 (2 floats/instr, cheaper than the
// bf16 unpack it replaces). agg outputs stay bf16 (swizzled) for the GEMM
// DMA consumers. Everything else identical to R22/R26 (288us, passing):
// BM=64 single-buffered swizzled DMA-LDS GEMMs, bucketed CSR build,
// 8-edge decode.
// ---------------------------------------------------------------------------

typedef unsigned short ushort_t;
typedef __attribute__((ext_vector_type(8))) short s8v;   // 8 bf16 (4 VGPRs)
typedef __attribute__((ext_vector_type(4))) float f4;    // MFMA accumulator
typedef __attribute__((ext_vector_type(2))) float f2v;   // fp8 cvt result

#define BSHIFT 8                       // nodes per bucket = 256 (N<=65536)

__device__ __forceinline__ ushort_t f2bf(float v) {
    unsigned u = __float_as_uint(v);
    return (ushort_t)((u + 0x7FFFu + ((u >> 16) & 1u)) >> 16);
}

__device__ __forceinline__ s8v cvt8(f4 v0, f4 v1) {
    ushort_t hb[8];
    hb[0] = f2bf(v0.x); hb[1] = f2bf(v0.y); hb[2] = f2bf(v0.z); hb[3] = f2bf(v0.w);
    hb[4] = f2bf(v1.x); hb[5] = f2bf(v1.y); hb[6] = f2bf(v1.z); hb[7] = f2bf(v1.w);
    return *(s8v*)hb;
}

// f32 -> OCP e4m3 byte (hardware converter)
__device__ __forceinline__ unsigned char f2fp8(float v) {
    int pk = __builtin_amdgcn_cvt_pk_fp8_f32(v, v, 0, false);
    return (unsigned char)(pk & 0xFF);
}

// swizzled ushort index within a row of width Wd: chunk c=(k&63)>>3 XOR row&7
__device__ __forceinline__ size_t swzidx(int row, int k, int Wd) {
    int p = (((k & 63) >> 3) ^ (row & 7));
    return (size_t)row * Wd + (k & ~63) + p * 8 + (k & 7);
}

// async 16B/lane global->LDS DMA; lds base must be wave-uniform
__device__ __forceinline__ void dma16(const ushort_t* g, ushort_t* l) {
    __builtin_amdgcn_global_load_lds(
        (const __attribute__((address_space(1))) unsigned int*)g,
        (__attribute__((address_space(3))) unsigned int*)l, 16, 0, 0);
}

// acc[16] += m * decode16_fp8(uint4)
__device__ __forceinline__ void add16(float* a, uint4 u, float m) {
    f2v p;
    p = __builtin_amdgcn_cvt_pk_f32_fp8((int)u.x, false); a[0]  = fmaf(p.x, m, a[0]);  a[1]  = fmaf(p.y, m, a[1]);
    p = __builtin_amdgcn_cvt_pk_f32_fp8((int)u.x, true);  a[2]  = fmaf(p.x, m, a[2]);  a[3]  = fmaf(p.y, m, a[3]);
    p = __builtin_amdgcn_cvt_pk_f32_fp8((int)u.y, false); a[4]  = fmaf(p.x, m, a[4]);  a[5]  = fmaf(p.y, m, a[5]);
    p = __builtin_amdgcn_cvt_pk_f32_fp8((int)u.y, true);  a[6]  = fmaf(p.x, m, a[6]);  a[7]  = fmaf(p.y, m, a[7]);
    p = __builtin_amdgcn_cvt_pk_f32_fp8((int)u.z, false); a[8]  = fmaf(p.x, m, a[8]);  a[9]  = fmaf(p.y, m, a[9]);
    p = __builtin_amdgcn_cvt_pk_f32_fp8((int)u.z, true);  a[10] = fmaf(p.x, m, a[10]); a[11] = fmaf(p.y, m, a[11]);
    p = __builtin_amdgcn_cvt_pk_f32_fp8((int)u.w, false); a[12] = fmaf(p.x, m, a[12]); a[13] = fmaf(p.y, m, a[13]);
    p = __builtin_amdgcn_cvt_pk_f32_fp8((int)u.w, true);  a[14] = fmaf(p.x, m, a[14]); a[15] = fmaf(p.y, m, a[15]);
}

// ---------------- fp32 -> bf16 bulk convert (swizzled rows of width W) ------
template <int W>
__global__ __launch_bounds__(256) void f2bswz_kernel(const float* __restrict__ in,
                                                     ushort_t* __restrict__ out, size_t n) {
    size_t i = ((size_t)blockIdx.x * 256 + threadIdx.x) * 8;
    if (i + 8 > n) return;
    f4 v0 = *(const f4*)&in[i];
    f4 v1 = *(const f4*)&in[i + 4];
    int row = (int)(i / W), k = (int)(i % W);
    *(s8v*)&out[swzidx(row, k, W)] = cvt8(v0, v1);
}

// ---------------- LDS-staged MFMA GEMM (BM=64, single-buffer + swizzle) -----
// OUTMODE: 0 fp32, 2 bf16, 3 fp32+bf16, 4 fp8 (linear bytes via Ch ptr).
template <int BN, int KW, int K1, bool A1F32, bool RELU, bool SCALE, bool DUAL,
          int OUTMODE, bool SWZO>
__global__ __launch_bounds__(256, 2) void gemm_lds(
    const float* __restrict__ A1f, const ushort_t* __restrict__ A1h,
    const ushort_t* __restrict__ A2h,
    const ushort_t* __restrict__ Wt,
    const float* __restrict__ bias, const float* __restrict__ rowscale,
    float* __restrict__ Cf, ushort_t* __restrict__ Ch,
    int M, int Nout)
{
    constexpr int NT = BN / 32;
    constexpr int K2 = KW - K1;
    __shared__ ushort_t Abuf[64 * 64];       // 8 KB
    __shared__ ushort_t Bbuf[BN * 64];       // 16/8 KB

    const int tid  = threadIdx.x;
    const int lane = tid & 63;
    const int w    = tid >> 6;
    const int wr   = w >> 1, wc = w & 1;
    const int rbase = blockIdx.y * 64;
    const int bn    = blockIdx.x * BN;

    f4 acc[2][NT];
    const f4 zero = {0.f, 0.f, 0.f, 0.f};
#pragma unroll
    for (int mi = 0; mi < 2; ++mi)
#pragma unroll
        for (int ni = 0; ni < NT; ++ni) acc[mi][ni] = zero;

    for (int kt = 0; kt < KW; kt += 64) {
        if constexpr (A1F32) {
#pragma unroll
            for (int j = 0; j < 2; ++j) {
                const int c2 = tid + j * 256;          // 0..511
                const int row = c2 >> 3, c = c2 & 7;
                const int gr = min(rbase + row, M - 1);
                const float* p = &A1f[(size_t)gr * K1 + kt + c * 8];
                const int pc = c ^ (row & 7);
                *(s8v*)&Abuf[row * 64 + pc * 8] = cvt8(*(const f4*)p, *(const f4*)(p + 4));
            }
        } else {
#pragma unroll
            for (int i = 0; i < 2; ++i) {
                const int s = w * 2 + i;               // 1KB slab (8 rows)
                const int row = s * 8 + (lane >> 3);
                const int c = lane & 7;
                const int gr = min(rbase + row, M - 1);
                const ushort_t* g;
                if (DUAL && kt >= K1) g = &A2h[(size_t)gr * K2 + (kt - K1) + c * 8];
                else                  g = &A1h[(size_t)gr * K1 + kt + c * 8];
                dma16(g, &Abuf[s * 512]);
            }
        }
#pragma unroll
        for (int i = 0; i < NT; ++i) {
            const int s = w * NT + i;                  // 1KB slab (8 cols)
            const int colr = s * 8 + (lane >> 3);
            const int c = lane & 7;
            dma16(&Wt[(size_t)(bn + colr) * KW + kt + c * 8], &Bbuf[s * 512]);
        }
        __syncthreads();
#pragma unroll
        for (int ks = 0; ks < 2; ++ks) {
            const int c = ks * 4 + (lane >> 4);
            s8v bfrag[NT];
#pragma unroll
            for (int ni = 0; ni < NT; ++ni) {
                const int colr = wc * (NT * 16) + ni * 16 + (lane & 15);
                bfrag[ni] = *(const s8v*)&Bbuf[colr * 64 + (c ^ (colr & 7)) * 8];
            }
#pragma unroll
            for (int mi = 0; mi < 2; ++mi) {
                const int row = wr * 32 + mi * 16 + (lane & 15);
                const s8v af = *(const s8v*)&Abuf[row * 64 + (c ^ (row & 7)) * 8];
#pragma unroll
                for (int ni = 0; ni < NT; ++ni)
                    acc[mi][ni] = __builtin_amdgcn_mfma_f32_16x16x32_bf16(af, bfrag[ni], acc[mi][ni], 0, 0, 0);
            }
        }
        __syncthreads();
    }

#pragma unroll
    for (int mi = 0; mi < 2; ++mi) {
#pragma unroll
        for (int reg = 0; reg < 4; ++reg) {
            const int row = rbase + wr * 32 + mi * 16 + (lane >> 4) * 4 + reg;
            if (row >= M) continue;
            const float rs = SCALE ? rowscale[row] : 1.f;
#pragma unroll
            for (int ni = 0; ni < NT; ++ni) {
                const int col = bn + wc * (NT * 16) + ni * 16 + (lane & 15);
                float v = acc[mi][ni][reg];
                if (SCALE) v *= rs;
                if (bias) v += bias[col];
                if (RELU) v = fmaxf(v, 0.f);
                const size_t oidx = SWZO ? swzidx(row, col, Nout) : ((size_t)row * Nout + col);
                if constexpr (OUTMODE == 2) {
                    Ch[oidx] = f2bf(v);
                } else if constexpr (OUTMODE == 3) {
                    Cf[(size_t)row * Nout + col] = v;
                    Ch[oidx] = f2bf(v);
                } else if constexpr (OUTMODE == 4) {
                    ((unsigned char*)Ch)[(size_t)row * Nout + col] = f2fp8(v);
                } else {
                    Cf[(size_t)row * Nout + col] = v;
                }
            }
        }
    }
}

// ---------------- weight transpose + bf16 convert (chunk-swizzled) ----------
struct WDesc { const float* W; ushort_t* h; int K; int No; };
struct WAll { WDesc d[6]; };

__global__ void wtcvt_kernel(WAll wa) {
    WDesc d = wa.d[blockIdx.y];
    int e = blockIdx.x * blockDim.x + threadIdx.x;
    if (e >= d.K * d.No) return;
    int k = e / d.No, n = e - k * d.No;
    d.h[swzidx(n, k, d.K)] = f2bf(d.W[e]);
}

// ---------------- bucketed CSR build ----------------------------------------
__global__ __launch_bounds__(256) void bcount_kernel(const int* __restrict__ dst,
                                                     int* __restrict__ bcount, int E, int NB) {
    __shared__ int cnt[256];
    const int t = threadIdx.x;
    if (t < NB) cnt[t] = 0;
    __syncthreads();
    for (int e = blockIdx.x * 256 + t; e < E; e += gridDim.x * 256)
        atomicAdd(&cnt[dst[e] >> BSHIFT], 1);
    __syncthreads();
    if (t < NB && cnt[t]) atomicAdd(&bcount[t], cnt[t]);
}

__global__ __launch_bounds__(256) void bscan_kernel(const int* __restrict__ bcount,
                                                    int* __restrict__ bbase,
                                                    int* __restrict__ bcursor, int NB, int E) {
    __shared__ int s[256];
    const int t = threadIdx.x;
    s[t] = (t < NB) ? bcount[t] : 0;
    __syncthreads();
    for (int off = 1; off < 256; off <<= 1) {
        int v = (t >= off) ? s[t - off] : 0;
        __syncthreads();
        s[t] += v;
        __syncthreads();
    }
    int excl = t ? s[t - 1] : 0;
    if (t < NB) { bbase[t] = excl; bcursor[t] = excl; }
    if (t == 0) bbase[NB] = E;
}

__global__ __launch_bounds__(256) void bpart_kernel(const int* __restrict__ src,
                                                    const int* __restrict__ dst,
                                                    int* __restrict__ bcursor,
                                                    unsigned* __restrict__ packed, int E, int NB) {
    __shared__ int cnt[256];
    __shared__ int cur[256];
    const int t = threadIdx.x;
    const int beg = blockIdx.x * 8192;
    const int end = min(beg + 8192, E);
    if (t < NB) cnt[t] = 0;
    __syncthreads();
    for (int e = beg + t; e < end; e += 256) atomicAdd(&cnt[dst[e] >> BSHIFT], 1);
    __syncthreads();
    if (t < NB && cnt[t]) cur[t] = atomicAdd(&bcursor[t], cnt[t]);
    __syncthreads();
    for (int e = beg + t; e < end; e += 256) {
        int d = dst[e];
        int b = d >> BSHIFT;
        int pos = atomicAdd(&cur[b], 1);
        packed[pos] = (unsigned)src[e] | ((unsigned)(d & ((1 << BSHIFT) - 1)) << 16);
    }
}

__global__ __launch_bounds__(256) void bbuild_kernel(const int* __restrict__ bbase,
                                                     const unsigned* __restrict__ packed,
                                                     int* __restrict__ col,
                                                     int* __restrict__ rowstart,
                                                     float* __restrict__ dinv, int N, int E) {
    __shared__ int ncnt[256];
    __shared__ int s[256];
    __shared__ int ncur[256];
    const int b = blockIdx.x;
    const int t = threadIdx.x;
    const int beg = bbase[b], end = bbase[b + 1];
    const int node0 = b << BSHIFT;
    const int nInB = min(256, N - node0);
    ncnt[t] = 0;
    __syncthreads();
    for (int e = beg + t; e < end; e += 256) atomicAdd(&ncnt[packed[e] >> 16], 1);
    __syncthreads();
    s[t] = ncnt[t];
    __syncthreads();
    for (int off = 1; off < 256; off <<= 1) {
        int v = (t >= off) ? s[t - off] : 0;
        __syncthreads();
        s[t] += v;
        __syncthreads();
    }
    int excl = t ? s[t - 1] : 0;
    if (t < nInB) {
        rowstart[node0 + t] = beg + excl;
        dinv[node0 + t] = rsqrtf((float)ncnt[t] + 1.0f);
    }
    ncur[t] = beg + excl;
    __syncthreads();
    for (int e = beg + t; e < end; e += 256) {
        unsigned p = packed[e];
        int pos = atomicAdd(&ncur[p >> 16], 1);
        col[pos] = (int)(p & 0xFFFFu);
    }
    if (b == 0 && t == 0) rowstart[N] = E;
}

// ---------------- fp8 wide-row CSR gather -----------------------------------
// F=128: fp8 row = 128B = 8 uint4 -> 8 lanes/row, 8 edges per wave-load.
// F=64:  fp8 row =  64B = 4 uint4 -> 4 lanes/row, 16 edges per load.
// Each lane holds 16 features; output packed to SWIZZLED bf16 agg rows.
template <int F>
__global__ __launch_bounds__(256) void gatherf8_kernel(const int* __restrict__ rowstart,
                                                       const int* __restrict__ col,
                                                       const float* __restrict__ dinv,
                                                       const unsigned char* __restrict__ hws8,
                                                       const float* __restrict__ bias,
                                                       ushort_t* __restrict__ aggb, int N) {
    constexpr int RW  = F / 16;            // uint4s per fp8 row (8 or 4)
    constexpr int EPG = 64 / RW;           // edges per wave-load (8 or 16)
    const int wave = threadIdx.x >> 6;
    const int lane = threadIdx.x & 63;
    const int d = blockIdx.x * 4 + wave;
    if (d >= N) return;
    const int beg = rowstart[d], end = rowstart[d + 1];
    const float dd = dinv[d];
    const uint4* rowp = (const uint4*)hws8;
    const int q = lane / RW;               // edge sub-slot
    const int c = lane % RW;               // uint4 slot within row

    float acc[16] = {};
    {
        uint4 sv = rowp[(size_t)d * RW + c];
        if (q == 0) add16(acc, sv, 1.f);
    }
    for (int e0 = beg; e0 < end; e0 += 64) {
        int nid = (e0 + lane < end) ? col[e0 + lane] : 0;
        int cnt = min(64, end - e0);
        for (int jj = 0; jj < cnt; jj += EPG) {
            int s = __shfl(nid, jj + q);
            float m = (jj + q < cnt) ? 1.f : 0.f;
            uint4 u = rowp[(size_t)s * RW + c];
            add16(acc, u, m);
        }
    }
#pragma unroll
    for (int i = 0; i < 16; ++i) {
        acc[i] += __shfl_down(acc[i], 32);
        acc[i] += __shfl_down(acc[i], 16);
        acc[i] += __shfl_down(acc[i], 8);
        if (RW <= 4) acc[i] += __shfl_down(acc[i], 4);
    }
    if (q == 0) {
        const int kb = c * 16;             // first feature handled by this lane
        f4 b0 = *(const f4*)&bias[kb];
        f4 b1 = *(const f4*)&bias[kb + 4];
        f4 b2 = *(const f4*)&bias[kb + 8];
        f4 b3 = *(const f4*)&bias[kb + 12];
        float r[16];
        r[0]  = fmaxf(acc[0]  * dd + b0.x, 0.f); r[1]  = fmaxf(acc[1]  * dd + b0.y, 0.f);
        r[2]  = fmaxf(acc[2]  * dd + b0.z, 0.f); r[3]  = fmaxf(acc[3]  * dd + b0.w, 0.f);
        r[4]  = fmaxf(acc[4]  * dd + b1.x, 0.f); r[5]  = fmaxf(acc[5]  * dd + b1.y, 0.f);
        r[6]  = fmaxf(acc[6]  * dd + b1.z, 0.f); r[7]  = fmaxf(acc[7]  * dd + b1.w, 0.f);
        r[8]  = fmaxf(acc[8]  * dd + b2.x, 0.f); r[9]  = fmaxf(acc[9]  * dd + b2.y, 0.f);
        r[10] = fmaxf(acc[10] * dd + b2.z, 0.f); r[11] = fmaxf(acc[11] * dd + b2.w, 0.f);
        r[12] = fmaxf(acc[12] * dd + b3.x, 0.f); r[13] = fmaxf(acc[13] * dd + b3.y, 0.f);
        r[14] = fmaxf(acc[14] * dd + b3.z, 0.f); r[15] = fmaxf(acc[15] * dd + b3.w, 0.f);
        uint4 o0, o1;
        o0.x = (unsigned)f2bf(r[0])  | ((unsigned)f2bf(r[1])  << 16);
        o0.y = (unsigned)f2bf(r[2])  | ((unsigned)f2bf(r[3])  << 16);
        o0.z = (unsigned)f2bf(r[4])  | ((unsigned)f2bf(r[5])  << 16);
        o0.w = (unsigned)f2bf(r[6])  | ((unsigned)f2bf(r[7])  << 16);
        o1.x = (unsigned)f2bf(r[8])  | ((unsigned)f2bf(r[9])  << 16);
        o1.y = (unsigned)f2bf(r[10]) | ((unsigned)f2bf(r[11]) << 16);
        o1.z = (unsigned)f2bf(r[12]) | ((unsigned)f2bf(r[13]) << 16);
        o1.w = (unsigned)f2bf(r[14]) | ((unsigned)f2bf(r[15]) << 16);
        const int g   = kb >> 6;                       // 64-feature group
        const int ch0 = ((kb & 63) >> 3) ^ (d & 7);    // swizzled chunk of o0
        const int ch1 = (((kb & 63) >> 3) + 1) ^ (d & 7);
        ((uint4*)aggb)[(size_t)d * (F / 8) + g * 8 + ch0] = o0;
        ((uint4*)aggb)[(size_t)d * (F / 8) + g * 8 + ch1] = o1;
    }
}

// ---------------- edge decode: 8 edges per wave, 16B/lane -------------------
__global__ __launch_bounds__(256) void decode8_kernel(const ushort_t* __restrict__ emb1b,
                                                      const int* __restrict__ eli,
                                                      const float* __restrict__ Wpost,
                                                      const float* __restrict__ bpost,
                                                      float* __restrict__ pred, int L) {
    const int wave = threadIdx.x >> 6;
    const int lane = threadIdx.x & 63;
    const int l8 = (blockIdx.x * 4 + wave) * 8;
    if (l8 >= L) return;
    const int q = lane >> 3;
    const int c = lane & 7;
    const int l = min(l8 + q, L - 1);
    const int s = eli[l];
    const int d = eli[L + l];
    const uint4* rowp = (const uint4*)emb1b;
    uint4 ua = rowp[(size_t)s * 8 + c];
    uint4 ub = rowp[(size_t)d * 8 + c];
    f4 w0 = *(const f4*)&Wpost[c * 16];
    f4 w1 = *(const f4*)&Wpost[c * 16 + 4];
    f4 w2 = *(const f4*)&Wpost[c * 16 + 8];
    f4 w3 = *(const f4*)&Wpost[c * 16 + 12];
    float p = 0.f;
    p += __uint_as_float(ua.x << 16) * __uint_as_float(ub.x << 16) * (w0.x + w0.y);
    p += __uint_as_float(ua.x & 0xFFFF0000u) * __uint_as_float(ub.x & 0xFFFF0000u) * (w0.z + w0.w);
    p += __uint_as_float(ua.y << 16) * __uint_as_float(ub.y << 16) * (w1.x + w1.y);
    p += __uint_as_float(ua.y & 0xFFFF0000u) * __uint_as_float(ub.y & 0xFFFF0000u) * (w1.z + w1.w);
    p += __uint_as_float(ua.z << 16) * __uint_as_float(ub.z << 16) * (w2.x + w2.y);
    p += __uint_as_float(ua.z & 0xFFFF0000u) * __uint_as_float(ub.z & 0xFFFF0000u) * (w2.z + w2.w);
    p += __uint_as_float(ua.w << 16) * __uint_as_float(ub.w << 16) * (w3.x + w3.y);
    p += __uint_as_float(ua.w & 0xFFFF0000u) * __uint_as_float(ub.w & 0xFFFF0000u) * (w3.z + w3.w);
    p += __shfl_down(p, 4);
    p += __shfl_down(p, 2);
    p += __shfl_down(p, 1);
    if (c == 0 && l8 + q < L) pred[l8 + q] = p + bpost[0] + bpost[1];
}

// ---------------------------------------------------------------------------
extern "C" void kernel_launch(void* const* d_in, const int* in_sizes, int n_in,
                              void* d_out, int out_size, void* d_ws, size_t ws_size,
                              hipStream_t stream) {
    const float* x     = (const float*)d_in[0];
    const float* prev0 = (const float*)d_in[1];
    const float* prev1 = (const float*)d_in[2];
    const float* Wpre1 = (const float*)d_in[3];
    const float* bpre1 = (const float*)d_in[4];
    const float* Wpre2 = (const float*)d_in[5];
    const float* bpre2 = (const float*)d_in[6];
    const float* Wc1   = (const float*)d_in[7];
    const float* bc1   = (const float*)d_in[8];
    const float* Wc2   = (const float*)d_in[9];
    const float* bc2   = (const float*)d_in[10];
    const float* Wm1   = (const float*)d_in[11];
    const float* bm1   = (const float*)d_in[12];
    const float* Wm2   = (const float*)d_in[13];
    const float* bm2   = (const float*)d_in[14];
    const float* Wpost = (const float*)d_in[15];
    const float* bpost = (const float*)d_in[16];
    const int* edge_index = (const int*)d_in[17];
    const int* eli        = (const int*)d_in[18];

    const int N = in_sizes[0] / 256;   // 50000  (must be <= 65536 for packing)
    const int E = in_sizes[17] / 2;    // 1.6M
    const int L = in_sizes[18] / 2;    // 200K
    const int NB = (N + 255) >> BSHIFT;

    const int* src = edge_index;
    const int* dst = edge_index + E;

    float* out  = (float*)d_out;
    float* pred = out;                        // [L]
    float* emb0 = out + L;                    // [N,128]
    float* emb1 = out + L + (size_t)N * 128;  // [N,64]

    // ---- workspace layout (FLOAT-SLOT offsets; R17/R20 map, verified) ----
    float* ws = (float*)d_ws;
    unsigned* packed = (unsigned*)ws;                      // [0,32N) pre-G1
    ushort_t* h1h   = (ushort_t*)ws;                       // [0,128N) G1->G2 (swz)
    unsigned char* hws1b8 = (unsigned char*)ws;            // [0,32N)  G3->gather1 (fp8 lin)
    ushort_t* emb0b = (ushort_t*)ws;                       // [0,64N)  G5->G6 (swz)
    ushort_t* emb1b = (ushort_t*)ws;                       // [0,32N)  G8->decode (lin)
    ushort_t* agg1b = (ushort_t*)(ws + (size_t)64 * N);    // [64N,128N) (swz)
    unsigned char* hws2b8 = (unsigned char*)(ws + (size_t)64 * N); // [64N,80N) (fp8 lin)
    ushort_t* agg2b = (ushort_t*)(ws + (size_t)96 * N);    // [96N,128N) (swz)
    ushort_t* h2b   = (ushort_t*)(ws + (size_t)128 * N);   // [128N,192N) (swz)
    ushort_t* p0b   = (ushort_t*)(ws + (size_t)192 * N);   // [192N,256N) (swz)
    ushort_t* p1b   = (ushort_t*)(ws + (size_t)256 * N);   // [256N,288N) (swz)
    int*      col   = (int*)(ws + (size_t)288 * N);        // [288N,320N)

    size_t o = (size_t)320 * N;
    int* rowstart = (int*)(ws + o);         o += ((size_t)N + 4) & ~(size_t)3;
    float* dinv = ws + o;                   o += ((size_t)N + 3) & ~(size_t)3;
    int* bbase = (int*)(ws + o);            o += 260;
    int* bcursor = (int*)(ws + o);          o += 260;
    int* bcount = (int*)(ws + o);           o += 260;
    ushort_t* wb = (ushort_t*)(ws + o);     // 163840 ushorts (16B-aligned)

    ushort_t* wpre1t = wb + 0;        // [256][256] swz
    ushort_t* wpre2t = wb + 65536;    // [128][256] swz
    ushort_t* wc1t   = wb + 98304;    // [128][128] swz
    ushort_t* wm1t   = wb + 114688;   // [128][256] swz
    ushort_t* wc2t   = wb + 147456;   // [64][128] swz
    ushort_t* wm2t   = wb + 155648;   // [64][128] swz

    // 0) prev0/prev1 -> bf16 (swizzled)
    {
        size_t n0 = (size_t)N * 128, n1 = (size_t)N * 64;
        f2bswz_kernel<128><<<(int)((n0 / 8 + 255) / 256), 256, 0, stream>>>(prev0, p0b, n0);
        f2bswz_kernel<64><<<(int)((n1 / 8 + 255) / 256), 256, 0, stream>>>(prev1, p1b, n1);
    }

    // 0a) bucketed CSR build + dinv
    hipMemsetAsync(bcount, 0, (size_t)NB * sizeof(int), stream);
    bcount_kernel<<<1024, 256, 0, stream>>>(dst, bcount, E, NB);
    bscan_kernel<<<1, 256, 0, stream>>>(bcount, bbase, bcursor, NB, E);
    bpart_kernel<<<(E + 8191) / 8192, 256, 0, stream>>>(src, dst, bcursor, packed, E, NB);
    bbuild_kernel<<<NB, 256, 0, stream>>>(bbase, packed, col, rowstart, dinv, N, E);

    // 0b) weights: transpose + bf16 convert, chunk-swizzled [Nout][K]
    WAll wa;
    wa.d[0] = {Wpre1, wpre1t, 256, 256};
    wa.d[1] = {Wpre2, wpre2t, 256, 128};
    wa.d[2] = {Wc1,   wc1t,   128, 128};
    wa.d[3] = {Wm1,   wm1t,   256, 128};
    wa.d[4] = {Wc2,   wc2t,   128, 64};
    wa.d[5] = {Wm2,   wm2t,   128, 64};
    wtcvt_kernel<<<dim3(256, 6), 256, 0, stream>>>(wa);

    const int gy = (N + 63) / 64;   // 782 row blocks

    // 1) h1 = bf16(relu(x@Wpre1+b))           [N,256]  K=256, fp32 A
    gemm_lds<128, 256, 256, true, true, false, false, 2, true><<<dim3(2, gy), 256, 0, stream>>>(
        x, nullptr, nullptr, wpre1t, bpre1, nullptr, nullptr, h1h, N, 256);
    // 2) h2 = bf16(relu(h1@Wpre2+b))          [N,128]  K=256, DMA
    gemm_lds<128, 256, 256, false, true, false, false, 2, true><<<dim3(1, gy), 256, 0, stream>>>(
        nullptr, h1h, nullptr, wpre2t, bpre2, nullptr, nullptr, h2b, N, 128);
    // 3) hws1 = fp8((h2@Wc1)*dinv[row])       [N,128]  K=128  (fp8 linear out)
    gemm_lds<128, 128, 128, false, false, true, false, 4, false><<<dim3(1, gy), 256, 0, stream>>>(
        nullptr, h2b, nullptr, wc1t, nullptr, dinv, nullptr, (ushort_t*)hws1b8, N, 128);
    // 4) agg1 = bf16(relu(dinv*(hws1[d]+sum hws1[s])+bc1))  (fp8 gather, swz out)
    gatherf8_kernel<128><<<(N + 3) / 4, 256, 0, stream>>>(rowstart, col, dinv, hws1b8, bc1, agg1b, N);
    // 5) emb0 = [agg1,prev0]@Wm1+bm1 (fp32 + swz bf16 copy)  [N,128]  K=128+128
    gemm_lds<128, 256, 128, false, false, false, true, 3, true><<<dim3(1, gy), 256, 0, stream>>>(
        nullptr, agg1b, p0b, wm1t, bm1, nullptr, emb0, emb0b, N, 128);
    // 6) hws2 = fp8((emb0@Wc2)*dinv[row])     [N,64]   K=128  (fp8 linear out)
    gemm_lds<64, 128, 128, false, false, true, false, 4, false><<<dim3(1, gy), 256, 0, stream>>>(
        nullptr, emb0b, nullptr, wc2t, nullptr, dinv, nullptr, (ushort_t*)hws2b8, N, 64);
    // 7) agg2 = bf16(relu(dinv*(hws2[d]+sum hws2[s])+bc2))  (fp8 gather, swz out)
    gatherf8_kernel<64><<<(N + 3) / 4, 256, 0, stream>>>(rowstart, col, dinv, hws2b8, bc2, agg2b, N);
    // 8) emb1 = [agg2,prev1]@Wm2+bm2 (fp32 + linear bf16 copy)  [N,64]  K=64+64
    gemm_lds<64, 128, 64, false, false, false, true, 3, false><<<dim3(1, gy), 256, 0, stream>>>(
        nullptr, agg2b, p1b, wm2t, bm2, nullptr, emb1, emb1b, N, 64);
    // 9) decode: 8 edges per wave
    decode8_kernel<<<(L + 31) / 32, 256, 0, stream>>>(emb1b, eli, Wpost, bpost, pred, L);
}